// Round 5
// baseline (316.483 us; speedup 1.0000x reference)
//
#include <hip/hip_runtime.h>

#define NCH 128
#define NGRAPH 64
#define SUB 16
#define CAP 64          // per-node edge bucket capacity (max in-degree ~45 for Poisson(16))

typedef _Float16 h8 __attribute__((ext_vector_type(8)));
typedef float f32x4 __attribute__((ext_vector_type(4)));
typedef float f32x2 __attribute__((ext_vector_type(2)));

// ---------------- f16/fp8 helpers ----------------

__device__ __forceinline__ unsigned pkh(float a, float b) {
    union { _Float16 h[2]; unsigned u; } x;
    x.h[0] = (_Float16)a; x.h[1] = (_Float16)b;
    return x.u;
}
__device__ __forceinline__ float flo(unsigned u) {
    union { unsigned u; _Float16 h[2]; } x; x.u = u; return (float)x.h[0];
}
__device__ __forceinline__ float fhi(unsigned u) {
    union { unsigned u; _Float16 h[2]; } x; x.u = u; return (float)x.h[1];
}
__device__ __forceinline__ unsigned short h16(float a) {
    union { _Float16 h; unsigned short s; } x; x.h = (_Float16)a; return x.s;
}

// dinv is a pure function of the bucket cursor: deg = cursor[n] - n*CAP.
__device__ __forceinline__ float dinv_of(int cur, int n) {
    return rsqrtf((float)(cur - n * CAP) + 1.0f);
}

// ---- setup: blocks [0,24) prep W frags; [24,24+gN) gstart; [24+gN,..) cursor init

__global__ __launch_bounds__(256) void k_setup(const float* __restrict__ W1,
                                               const float* __restrict__ W2,
                                               const float* __restrict__ W3,
                                               uint4* __restrict__ wfrag,
                                               const int* __restrict__ batch,
                                               int* __restrict__ gstart,
                                               int* __restrict__ cursor, int N, int gN) {
    if (blockIdx.x < 24) {
        // W frag: (c,nt,i=nl*4+q): 8 f16 = W[k=c*32+q*8+j][n=nt*16+nl] at
        // swizzled index i^((nl>>1)&7); layer stride 2048 frags = 32 KB.
        int gid = blockIdx.x * 256 + threadIdx.x;       // 0..6143
        int layer = gid >> 11;
        int fr = gid & 2047;
        int c = fr >> 9;
        int nt = (fr >> 6) & 7;
        int i = fr & 63;
        int nl = i >> 2, q = i & 3;
        int iS = i ^ ((nl >> 1) & 7);
        int n = nt * 16 + nl;
        int k0 = c * 32 + q * 8;
        const float* W = (layer == 0) ? W1 : (layer == 1) ? W2 : W3;
        union { unsigned short s[8]; uint4 u; } pk;
        #pragma unroll
        for (int j = 0; j < 8; j++)
            pk.s[j] = h16(W[(k0 + j) * NCH + n]);
        wfrag[layer * 2048 + (c * 8 + nt) * 64 + iS] = pk.u;
    } else if (blockIdx.x < 24 + gN) {
        int i = (blockIdx.x - 24) * 256 + threadIdx.x;
        if (i >= N) return;
        int b = batch[i];
        int prev = (i == 0) ? -1 : batch[i - 1];
        for (int g = prev + 1; g <= b; g++) gstart[g] = i;
        if (i == N - 1) {
            for (int g = b + 1; g <= NGRAPH; g++) gstart[g] = N;
        }
    } else {
        int i = (blockIdx.x - 24 - gN) * 256 + threadIdx.x;
        if (i < N) cursor[i] = i * CAP;
    }
}

// XCD-localized scatter (round-7 win: plain stores suffer cross-XCD
// write-allocate amplification; 8 dst-ranges keyed by blockIdx&7 fix it).
// Proven scalar form (R2).
__global__ __launch_bounds__(256) void k_fill(const int* __restrict__ src,
                                              const int* __restrict__ dst,
                                              int* __restrict__ cursor,
                                              int* __restrict__ edge_src, int E, int N) {
    int range = blockIdx.x & 7;
    int chunk = blockIdx.x >> 3;
    int r0 = (range * N) >> 3;
    int r1 = ((range + 1) * N) >> 3;
    int e = chunk * 256 + threadIdx.x;
    if (e >= E) return;
    int d = dst[e];
    if (d >= r0 && d < r1) {
        int p = atomicAdd(&cursor[d], 1);
        if (p < (d + 1) * CAP) edge_src[p] = src[e];   // guard never fires (max deg ~45)
    }
}

// ---- MFMA GEMM: fp8 SPLIT-TABLE out = dinv[r] * (A[N,128] @ W) ----
// This round: output split into TWO half-tables of 64-B rows (ch 0..63 and
// ch 64..127), each (N+64)*64 B = 3.2 MB -> fits a 4 MiB per-XCD L2 during
// its gather pass. Plain stores (R3 lesson: NO nontemporal on producer
// stores; the consumer must find the data in cache).

__global__ __launch_bounds__(256) void k_mmgemm(const void* __restrict__ Araw,
                                                const uint4* __restrict__ wfrag,
                                                const int* __restrict__ cursor,
                                                unsigned* __restrict__ D, int N,
                                                int a_fp32) {
    __shared__ uint4 Wl[2048];           // 32 KB
    int t = threadIdx.x;
    #pragma unroll
    for (int i = 0; i < 8; i++) Wl[i * 256 + t] = wfrag[i * 256 + t];

    int wv = t >> 6, lane = t & 63;
    int rowW = blockIdx.x * 64 + wv * 16;
    int m = lane & 15, q = lane >> 4;
    int aRow = rowW + m;

    union { uint4 u; h8 h; } a[4];
    if (a_fp32) {
        const float* Af = (const float*)Araw;
        #pragma unroll
        for (int c = 0; c < 4; c++) {
            union { _Float16 h[8]; uint4 u; } pk;
            #pragma unroll
            for (int j = 0; j < 8; j++) pk.h[j] = (_Float16)0.f;
            if (aRow < N) {
                float4 v0 = *reinterpret_cast<const float4*>(&Af[(size_t)aRow * NCH + c * 32 + q * 8]);
                float4 v1 = *reinterpret_cast<const float4*>(&Af[(size_t)aRow * NCH + c * 32 + q * 8 + 4]);
                pk.h[0] = (_Float16)v0.x; pk.h[1] = (_Float16)v0.y;
                pk.h[2] = (_Float16)v0.z; pk.h[3] = (_Float16)v0.w;
                pk.h[4] = (_Float16)v1.x; pk.h[5] = (_Float16)v1.y;
                pk.h[6] = (_Float16)v1.z; pk.h[7] = (_Float16)v1.w;
            }
            a[c].u = pk.u;
        }
    } else {
        const unsigned* A = (const unsigned*)Araw;
        #pragma unroll
        for (int c = 0; c < 4; c++) {
            a[c].u = make_uint4(0, 0, 0, 0);
            if (aRow < N)
                a[c].u = *reinterpret_cast<const uint4*>(&A[(size_t)aRow * 64 + c * 16 + q * 4]);
        }
    }

    __syncthreads();

    int iS = (m * 4 + q) ^ ((m >> 1) & 7);

    f32x4 acc[8];
    #pragma unroll
    for (int nt = 0; nt < 8; nt++) acc[nt] = (f32x4){0.f, 0.f, 0.f, 0.f};

    #pragma unroll
    for (int c = 0; c < 4; c++) {
        #pragma unroll
        for (int nt = 0; nt < 8; nt++) {
            union { uint4 u; h8 h; } b;
            b.u = Wl[(c * 8 + nt) * 64 + iS];
            acc[nt] = __builtin_amdgcn_mfma_f32_16x16x32_f16(a[c].h, b.h, acc[nt], 0, 0, 0);
        }
    }

    float dn[4];
    #pragma unroll
    for (int r = 0; r < 4; r++) {
        int rg = rowW + q * 4 + r;
        dn[r] = (rg < N) ? dinv_of(cursor[rg], rg) : 0.0f;
    }
    // fp8 epilogue: lane packs its byte (channel ch = nt*16+m), merge bytes
    // across lanes m..m+3 via two shfl_xor, lanes m%4==0 store a dword.
    // Half-table select: ch<64 (nt<4) -> table 0, else table 1. Row = 16 dw.
    size_t tabDw = (size_t)(N + 64) * 16;
    #pragma unroll
    for (int nt = 0; nt < 8; nt++) {
        unsigned* Dt = D + (nt >> 2) * tabDw;
        #pragma unroll
        for (int r = 0; r < 4; r++) {
            int rg = rowW + q * 4 + r;
            float v = acc[nt][r] * dn[r];
            unsigned b = __builtin_amdgcn_cvt_pk_fp8_f32(v, v, 0, false) & 0xffu;
            b |= ((unsigned)__shfl_xor((int)b, 1, 64)) << 8;
            b |= ((unsigned)__shfl_xor((int)b, 2, 64)) << 16;
            if ((lane & 3) == 0 && rg < N)
                Dt[(size_t)rg * 16 + (nt & 3) * 4 + (m >> 2)] = b;
        }
    }
}

// ---- gather: relu(dinv*(self + sum_edges) + b), HALF-TABLE pass ----
// Called twice per layer (half=0: ch 0..63, half=1: ch 64..127). The active
// half-table is 3.2 MB -> per-XCD L2-resident after warm fill; all random
// row reads become L2 hits. Per edge per lane: 1 byte load + 1 cvt + 1 add.
// Summation order per channel is identical to the single-pass version.
// Output f16 (ushort per lane, 128 B per wave, coalesced).

__global__ __launch_bounds__(256) void k_gather(const unsigned char* __restrict__ hw,
                                                const float* __restrict__ bias,
                                                const int* __restrict__ cursor,
                                                const int* __restrict__ edge_src,
                                                unsigned short* __restrict__ out,
                                                int N, int half) {
    int wv = threadIdx.x >> 6;
    int lane = threadIdx.x & 63;
    int n = blockIdx.x * 4 + wv;
    if (n >= N) return;
    const unsigned char* tab = hw + (size_t)half * (size_t)(N + 64) * 64;

    f32x2 v0 = __builtin_amdgcn_cvt_pk_f32_fp8((int)tab[(size_t)n * 64 + lane], false);
    float ax = v0.x;

    int j0 = n * CAP;
    int cur = cursor[n];
    int j1 = cur;
    if (j1 > j0 + CAP) j1 = j0 + CAP;
    int j = j0;
    for (; j + 15 < j1; j += 16) {
        unsigned u[16];
        #pragma unroll
        for (int i = 0; i < 16; i++)
            u[i] = tab[(size_t)edge_src[j + i] * 64 + lane];
        #pragma unroll
        for (int i = 0; i < 16; i++) {
            f32x2 v = __builtin_amdgcn_cvt_pk_f32_fp8((int)u[i], false);
            ax += v.x;
        }
    }
    for (; j + 7 < j1; j += 8) {
        unsigned u[8];
        #pragma unroll
        for (int i = 0; i < 8; i++)
            u[i] = tab[(size_t)edge_src[j + i] * 64 + lane];
        #pragma unroll
        for (int i = 0; i < 8; i++) {
            f32x2 v = __builtin_amdgcn_cvt_pk_f32_fp8((int)u[i], false);
            ax += v.x;
        }
    }
    for (; j + 1 < j1; j += 2) {
        unsigned u0 = tab[(size_t)edge_src[j + 0] * 64 + lane];
        unsigned u1 = tab[(size_t)edge_src[j + 1] * 64 + lane];
        f32x2 w0 = __builtin_amdgcn_cvt_pk_f32_fp8((int)u0, false);
        f32x2 w1 = __builtin_amdgcn_cvt_pk_f32_fp8((int)u1, false);
        ax += w0.x + w1.x;
    }
    if (j < j1) {
        unsigned u0 = tab[(size_t)edge_src[j] * 64 + lane];
        f32x2 w0 = __builtin_amdgcn_cvt_pk_f32_fp8((int)u0, false);
        ax += w0.x;
    }
    float dn = dinv_of(cur, n);
    float bb = bias[half * 64 + lane];
    float ox = fmaxf(ax * dn + bb, 0.0f);
    out[(size_t)n * 128 + half * 64 + lane] = h16(ox);
}

// ---------------- pooling (f16 in, fp32 partials) ----------------

__global__ __launch_bounds__(256) void k_poolA(const unsigned* __restrict__ h,
                                               const int* __restrict__ gstart,
                                               float* __restrict__ partial) {
    int g = blockIdx.x >> 4;
    int s = blockIdx.x & (SUB - 1);
    int c2 = threadIdx.x & 63;
    int r = threadIdx.x >> 6;          // 0..3
    int j0 = gstart[g], j1 = gstart[g + 1];
    int len = j1 - j0;
    int chunk = (len + SUB - 1) / SUB;
    int a0 = j0 + s * chunk;
    int a1 = a0 + chunk; if (a1 > j1) a1 = j1;
    float ax = 0.0f, ay = 0.0f;
    for (int j = a0 + r; j < a1; j += 4) {
        unsigned u = h[(size_t)j * 64 + c2];
        ax += flo(u); ay += fhi(u);
    }
    __shared__ float2 sh[4][64];
    sh[r][c2] = make_float2(ax, ay);
    __syncthreads();
    if (r == 0) {
        float sx = sh[0][c2].x + sh[1][c2].x + sh[2][c2].x + sh[3][c2].x;
        float sy = sh[0][c2].y + sh[1][c2].y + sh[2][c2].y + sh[3][c2].y;
        reinterpret_cast<float2*>(partial)[(size_t)(g * SUB + s) * 64 + c2] =
            make_float2(sx, sy);
    }
}

__global__ __launch_bounds__(128) void k_finalize(const float* __restrict__ partial,
                                                  const int* __restrict__ gstart,
                                                  const float* __restrict__ Wc,
                                                  const float* __restrict__ bc,
                                                  float* __restrict__ out) {
    int g = blockIdx.x;
    int c = threadIdx.x;
    float s = 0.0f;
    #pragma unroll
    for (int i = 0; i < SUB; i++) s += partial[(size_t)(g * SUB + i) * NCH + c];
    int len = gstart[g + 1] - gstart[g];
    __shared__ float sh[128];
    sh[c] = s / fmaxf((float)len, 1.0f);
    __syncthreads();
    if (c < 2) {
        float o = 0.0f;
        for (int k = 0; k < NCH; k++) o += sh[k] * Wc[k * 2 + c];
        out[g * 2 + c] = o + bc[c];
    }
}

// ---------------- launcher ----------------

extern "C" void kernel_launch(void* const* d_in, const int* in_sizes, int n_in,
                              void* d_out, int out_size, void* d_ws, size_t ws_size,
                              hipStream_t stream) {
    const float* x   = (const float*)d_in[0];
    const int* eidx  = (const int*)d_in[1];
    const int* batch = (const int*)d_in[2];
    const float* W1 = (const float*)d_in[3];
    const float* b1 = (const float*)d_in[4];
    const float* W2 = (const float*)d_in[5];
    const float* b2 = (const float*)d_in[6];
    const float* W3 = (const float*)d_in[7];
    const float* b3 = (const float*)d_in[8];
    const float* Wc = (const float*)d_in[9];
    const float* bc = (const float*)d_in[10];
    float* out = (float*)d_out;

    int N = in_sizes[0] / NCH;
    int E = in_sizes[1] / 2;
    const int* src = eidx;
    const int* dst = eidx + E;

    char* w = (char*)d_ws;
    auto alloc = [&](size_t bytes) -> void* {
        void* p = (void*)w;
        w += (bytes + 511) & ~(size_t)511;
        return p;
    };
    int*            cursor   = (int*)alloc((size_t)N * 4);
    int*            edge_src = (int*)alloc((size_t)N * CAP * 4);   // 12.8 MB buckets
    uint4*          wfrag    = (uint4*)alloc((size_t)3 * 2048 * 16);
    unsigned*       hwD      = (unsigned*)alloc((size_t)2 * (N + 64) * 64);  // 2 fp8 half-tables
    unsigned short* hbA      = (unsigned short*)alloc((size_t)N * 256);      // f16 activations
    unsigned short* hbB      = (unsigned short*)alloc((size_t)N * 256);
    float*          partial  = (float*)alloc((size_t)NGRAPH * SUB * NCH * 4);
    int*            gstart   = (int*)alloc((size_t)(NGRAPH + 1) * 4);

    int gE = (E + 255) / 256;
    int gN = (N + 255) / 256;

    k_setup<<<24 + 2 * gN, 256, 0, stream>>>(W1, W2, W3, wfrag, batch, gstart, cursor, N, gN);
    k_fill<<<gE * 8, 256, 0, stream>>>(src, dst, cursor, edge_src, E, N);

    int gM = (N + 63) / 64;
    int gA = (N + 3) / 4;
    const unsigned char* hw8 = (const unsigned char*)hwD;
    // layer 1 (reads fp32 x directly)
    k_mmgemm<<<gM, 256, 0, stream>>>(x, wfrag, cursor, hwD, N, 1);
    k_gather<<<gA, 256, 0, stream>>>(hw8, b1, cursor, edge_src, hbA, N, 0);
    k_gather<<<gA, 256, 0, stream>>>(hw8, b1, cursor, edge_src, hbA, N, 1);
    // layer 2
    k_mmgemm<<<gM, 256, 0, stream>>>(hbA, wfrag + 2048, cursor, hwD, N, 0);
    k_gather<<<gA, 256, 0, stream>>>(hw8, b2, cursor, edge_src, hbB, N, 0);
    k_gather<<<gA, 256, 0, stream>>>(hw8, b2, cursor, edge_src, hbB, N, 1);
    // layer 3
    k_mmgemm<<<gM, 256, 0, stream>>>(hbB, wfrag + 4096, cursor, hwD, N, 0);
    k_gather<<<gA, 256, 0, stream>>>(hw8, b3, cursor, edge_src, hbA, N, 0);
    k_gather<<<gA, 256, 0, stream>>>(hw8, b3, cursor, edge_src, hbA, N, 1);

    k_poolA<<<NGRAPH * SUB, 256, 0, stream>>>((const unsigned*)hbA, gstart, partial);
    k_finalize<<<NGRAPH, 128, 0, stream>>>(partial, gstart, Wc, bc, out);
}

// Round 6
// 247.333 us; speedup vs baseline: 1.2796x; 1.2796x over previous
//
#include <hip/hip_runtime.h>

#define NCH 128
#define NGRAPH 64
#define SUB 16
#define CAP 64          // per-node edge bucket capacity (max in-degree ~45 for Poisson(16))

typedef _Float16 h8 __attribute__((ext_vector_type(8)));
typedef float f32x4 __attribute__((ext_vector_type(4)));
typedef float f32x2 __attribute__((ext_vector_type(2)));

// ---------------- f16/fp8 helpers ----------------

__device__ __forceinline__ unsigned pkh(float a, float b) {
    union { _Float16 h[2]; unsigned u; } x;
    x.h[0] = (_Float16)a; x.h[1] = (_Float16)b;
    return x.u;
}
__device__ __forceinline__ float flo(unsigned u) {
    union { unsigned u; _Float16 h[2]; } x; x.u = u; return (float)x.h[0];
}
__device__ __forceinline__ float fhi(unsigned u) {
    union { unsigned u; _Float16 h[2]; } x; x.u = u; return (float)x.h[1];
}
__device__ __forceinline__ unsigned short h16(float a) {
    union { _Float16 h; unsigned short s; } x; x.h = (_Float16)a; return x.s;
}

// dinv is a pure function of the bucket cursor: deg = cursor[n] - n*CAP.
__device__ __forceinline__ float dinv_of(int cur, int n) {
    return rsqrtf((float)(cur - n * CAP) + 1.0f);
}

// ---- setup: blocks [0,24) prep W frags; [24,24+gN) gstart; [24+gN,..) cursor init

__global__ __launch_bounds__(256) void k_setup(const float* __restrict__ W1,
                                               const float* __restrict__ W2,
                                               const float* __restrict__ W3,
                                               uint4* __restrict__ wfrag,
                                               const int* __restrict__ batch,
                                               int* __restrict__ gstart,
                                               int* __restrict__ cursor, int N, int gN) {
    if (blockIdx.x < 24) {
        // W frag: (c,nt,i=nl*4+q): 8 f16 = W[k=c*32+q*8+j][n=nt*16+nl] at
        // swizzled index i^((nl>>1)&7); layer stride 2048 frags = 32 KB.
        int gid = blockIdx.x * 256 + threadIdx.x;       // 0..6143
        int layer = gid >> 11;
        int fr = gid & 2047;
        int c = fr >> 9;
        int nt = (fr >> 6) & 7;
        int i = fr & 63;
        int nl = i >> 2, q = i & 3;
        int iS = i ^ ((nl >> 1) & 7);
        int n = nt * 16 + nl;
        int k0 = c * 32 + q * 8;
        const float* W = (layer == 0) ? W1 : (layer == 1) ? W2 : W3;
        union { unsigned short s[8]; uint4 u; } pk;
        #pragma unroll
        for (int j = 0; j < 8; j++)
            pk.s[j] = h16(W[(k0 + j) * NCH + n]);
        wfrag[layer * 2048 + (c * 8 + nt) * 64 + iS] = pk.u;
    } else if (blockIdx.x < 24 + gN) {
        int i = (blockIdx.x - 24) * 256 + threadIdx.x;
        if (i >= N) return;
        int b = batch[i];
        int prev = (i == 0) ? -1 : batch[i - 1];
        for (int g = prev + 1; g <= b; g++) gstart[g] = i;
        if (i == N - 1) {
            for (int g = b + 1; g <= NGRAPH; g++) gstart[g] = N;
        }
    } else {
        int i = (blockIdx.x - 24 - gN) * 256 + threadIdx.x;
        if (i < N) cursor[i] = i * CAP;
    }
}

// XCD-localized scatter (round-7 win: plain stores suffer cross-XCD
// write-allocate amplification; 8 dst-ranges keyed by blockIdx&7 fix it).
// Proven scalar form (R2).
__global__ __launch_bounds__(256) void k_fill(const int* __restrict__ src,
                                              const int* __restrict__ dst,
                                              int* __restrict__ cursor,
                                              int* __restrict__ edge_src, int E, int N) {
    int range = blockIdx.x & 7;
    int chunk = blockIdx.x >> 3;
    int r0 = (range * N) >> 3;
    int r1 = ((range + 1) * N) >> 3;
    int e = chunk * 256 + threadIdx.x;
    if (e >= E) return;
    int d = dst[e];
    if (d >= r0 && d < r1) {
        int p = atomicAdd(&cursor[d], 1);
        if (p < (d + 1) * CAP) edge_src[p] = src[e];   // guard never fires (max deg ~45)
    }
}

// ---- MFMA GEMM: D[N,128](fp8 e4m3) = dinv[r] * (A[N,128] @ W) ----
// Table rows are fp8: one row = 128 B = ONE cache line for the gather.
// Writes a zero pad row at rg==N (gather's masked remainder reads it).
// Exact R2 structure (the 257.7us best).

__global__ __launch_bounds__(256) void k_mmgemm(const void* __restrict__ Araw,
                                                const uint4* __restrict__ wfrag,
                                                const int* __restrict__ cursor,
                                                unsigned* __restrict__ D, int N,
                                                int a_fp32) {
    __shared__ uint4 Wl[2048];           // 32 KB
    int t = threadIdx.x;
    #pragma unroll
    for (int i = 0; i < 8; i++) Wl[i * 256 + t] = wfrag[i * 256 + t];

    int wv = t >> 6, lane = t & 63;
    int rowW = blockIdx.x * 64 + wv * 16;
    int m = lane & 15, q = lane >> 4;
    int aRow = rowW + m;

    union { uint4 u; h8 h; } a[4];
    if (a_fp32) {
        const float* Af = (const float*)Araw;
        #pragma unroll
        for (int c = 0; c < 4; c++) {
            union { _Float16 h[8]; uint4 u; } pk;
            #pragma unroll
            for (int j = 0; j < 8; j++) pk.h[j] = (_Float16)0.f;
            if (aRow < N) {
                float4 v0 = *reinterpret_cast<const float4*>(&Af[(size_t)aRow * NCH + c * 32 + q * 8]);
                float4 v1 = *reinterpret_cast<const float4*>(&Af[(size_t)aRow * NCH + c * 32 + q * 8 + 4]);
                pk.h[0] = (_Float16)v0.x; pk.h[1] = (_Float16)v0.y;
                pk.h[2] = (_Float16)v0.z; pk.h[3] = (_Float16)v0.w;
                pk.h[4] = (_Float16)v1.x; pk.h[5] = (_Float16)v1.y;
                pk.h[6] = (_Float16)v1.z; pk.h[7] = (_Float16)v1.w;
            }
            a[c].u = pk.u;
        }
    } else {
        const unsigned* A = (const unsigned*)Araw;
        #pragma unroll
        for (int c = 0; c < 4; c++) {
            a[c].u = make_uint4(0, 0, 0, 0);
            if (aRow < N)
                a[c].u = *reinterpret_cast<const uint4*>(&A[(size_t)aRow * 64 + c * 16 + q * 4]);
        }
    }

    __syncthreads();

    int iS = (m * 4 + q) ^ ((m >> 1) & 7);

    f32x4 acc[8];
    #pragma unroll
    for (int nt = 0; nt < 8; nt++) acc[nt] = (f32x4){0.f, 0.f, 0.f, 0.f};

    #pragma unroll
    for (int c = 0; c < 4; c++) {
        #pragma unroll
        for (int nt = 0; nt < 8; nt++) {
            union { uint4 u; h8 h; } b;
            b.u = Wl[(c * 8 + nt) * 64 + iS];
            acc[nt] = __builtin_amdgcn_mfma_f32_16x16x32_f16(a[c].h, b.h, acc[nt], 0, 0, 0);
        }
    }

    float dn[4];
    #pragma unroll
    for (int r = 0; r < 4; r++) {
        int rg = rowW + q * 4 + r;
        dn[r] = (rg < N) ? dinv_of(cursor[rg], rg) : 0.0f;
    }
    // fp8 epilogue: each lane packs its own byte (channel nt*16+m), merge
    // bytes across lanes m..m+3 via two shfl_xor, lanes m%4==0 store a dword.
    #pragma unroll
    for (int nt = 0; nt < 8; nt++) {
        #pragma unroll
        for (int r = 0; r < 4; r++) {
            int rg = rowW + q * 4 + r;
            float v = acc[nt][r] * dn[r];
            unsigned b = __builtin_amdgcn_cvt_pk_fp8_f32(v, v, 0, false) & 0xffu;
            b |= ((unsigned)__shfl_xor((int)b, 1, 64)) << 8;
            b |= ((unsigned)__shfl_xor((int)b, 2, 64)) << 16;
            if ((lane & 3) == 0 && rg <= N)            // rg==N: zero pad row
                D[(size_t)rg * 32 + nt * 4 + (m >> 2)] = b;
        }
    }
}

// ---- gather: relu(dinv*(self + sum_edges) + b), fp8 table in, f16 out ----
// 1 wave/node; lane reads one ushort = 2 fp8 channels per row -> one 128-B
// line per edge. THIS ROUND: indices loaded cooperatively — lanes 0..15
// fetch 16 consecutive bucket entries in ONE coalesced 64-B request
// (4-way replicated across quarter-groups), then __shfl(idx, i, 16)
// broadcasts each index in-register. Replaces 16 scalar broadcast VMEM
// loads per batch -> ~halves gather VMEM request count. Remainder batch
// masks with pad row N (single L1-hot zero line). Per-lane edge summation
// order unchanged vs R2 -> bitwise-identical output.

__global__ __launch_bounds__(256) void k_gather(const unsigned short* __restrict__ hw,
                                                const float* __restrict__ bias,
                                                const int* __restrict__ cursor,
                                                const int* __restrict__ edge_src,
                                                unsigned* __restrict__ out, int N) {
    int wv = threadIdx.x >> 6;
    int lane = threadIdx.x & 63;
    int n = blockIdx.x * 4 + wv;
    if (n >= N) return;

    unsigned vs = hw[(size_t)n * 64 + lane];
    f32x2 v0 = __builtin_amdgcn_cvt_pk_f32_fp8((int)vs, false);
    float ax = v0.x, ay = v0.y;

    int j0 = n * CAP;
    int cur = cursor[n];
    int j1 = cur;
    if (j1 > j0 + CAP) j1 = j0 + CAP;

    int j = j0;
    for (; j + 16 <= j1; j += 16) {
        int myi = edge_src[j + (lane & 15)];       // one coalesced 64-B request
        unsigned u[16];
        #pragma unroll
        for (int i = 0; i < 16; i++) {
            int bi = __shfl(myi, i, 16);           // in-register broadcast
            u[i] = hw[(size_t)bi * 64 + lane];
        }
        #pragma unroll
        for (int i = 0; i < 16; i++) {
            f32x2 v = __builtin_amdgcn_cvt_pk_f32_fp8((int)u[i], false);
            ax += v.x; ay += v.y;
        }
    }
    int r = j1 - j;
    if (r > 0) {
        // reads within workspace (bucket region + pad); values past j1 are
        // garbage but masked to pad row N before use as an address.
        int myi = edge_src[j + (lane & 15)];
        unsigned u[16];
        #pragma unroll
        for (int i = 0; i < 16; i++) {
            int bi = __shfl(myi, i, 16);
            bi = (i < r) ? bi : N;                 // pad row N = zeros, L1-hot
            u[i] = hw[(size_t)bi * 64 + lane];
        }
        #pragma unroll
        for (int i = 0; i < 16; i++) {
            f32x2 v = __builtin_amdgcn_cvt_pk_f32_fp8((int)u[i], false);
            ax += v.x; ay += v.y;
        }
    }

    float dn = dinv_of(cur, n);
    float2 bb = reinterpret_cast<const float2*>(bias)[lane];
    float ox = fmaxf(ax * dn + bb.x, 0.0f);
    float oy = fmaxf(ay * dn + bb.y, 0.0f);
    out[(size_t)n * 64 + lane] = pkh(ox, oy);
}

// ---------------- pooling (f16 in, fp32 partials) ----------------

__global__ __launch_bounds__(256) void k_poolA(const unsigned* __restrict__ h,
                                               const int* __restrict__ gstart,
                                               float* __restrict__ partial) {
    int g = blockIdx.x >> 4;
    int s = blockIdx.x & (SUB - 1);
    int c2 = threadIdx.x & 63;
    int r = threadIdx.x >> 6;          // 0..3
    int j0 = gstart[g], j1 = gstart[g + 1];
    int len = j1 - j0;
    int chunk = (len + SUB - 1) / SUB;
    int a0 = j0 + s * chunk;
    int a1 = a0 + chunk; if (a1 > j1) a1 = j1;
    float ax = 0.0f, ay = 0.0f;
    for (int j = a0 + r; j < a1; j += 4) {
        unsigned u = h[(size_t)j * 64 + c2];
        ax += flo(u); ay += fhi(u);
    }
    __shared__ float2 sh[4][64];
    sh[r][c2] = make_float2(ax, ay);
    __syncthreads();
    if (r == 0) {
        float sx = sh[0][c2].x + sh[1][c2].x + sh[2][c2].x + sh[3][c2].x;
        float sy = sh[0][c2].y + sh[1][c2].y + sh[2][c2].y + sh[3][c2].y;
        reinterpret_cast<float2*>(partial)[(size_t)(g * SUB + s) * 64 + c2] =
            make_float2(sx, sy);
    }
}

__global__ __launch_bounds__(128) void k_finalize(const float* __restrict__ partial,
                                                  const int* __restrict__ gstart,
                                                  const float* __restrict__ Wc,
                                                  const float* __restrict__ bc,
                                                  float* __restrict__ out) {
    int g = blockIdx.x;
    int c = threadIdx.x;
    float s = 0.0f;
    #pragma unroll
    for (int i = 0; i < SUB; i++) s += partial[(size_t)(g * SUB + i) * NCH + c];
    int len = gstart[g + 1] - gstart[g];
    __shared__ float sh[128];
    sh[c] = s / fmaxf((float)len, 1.0f);
    __syncthreads();
    if (c < 2) {
        float o = 0.0f;
        for (int k = 0; k < NCH; k++) o += sh[k] * Wc[k * 2 + c];
        out[g * 2 + c] = o + bc[c];
    }
}

// ---------------- launcher ----------------

extern "C" void kernel_launch(void* const* d_in, const int* in_sizes, int n_in,
                              void* d_out, int out_size, void* d_ws, size_t ws_size,
                              hipStream_t stream) {
    const float* x   = (const float*)d_in[0];
    const int* eidx  = (const int*)d_in[1];
    const int* batch = (const int*)d_in[2];
    const float* W1 = (const float*)d_in[3];
    const float* b1 = (const float*)d_in[4];
    const float* W2 = (const float*)d_in[5];
    const float* b2 = (const float*)d_in[6];
    const float* W3 = (const float*)d_in[7];
    const float* b3 = (const float*)d_in[8];
    const float* Wc = (const float*)d_in[9];
    const float* bc = (const float*)d_in[10];
    float* out = (float*)d_out;

    int N = in_sizes[0] / NCH;
    int E = in_sizes[1] / 2;
    const int* src = eidx;
    const int* dst = eidx + E;

    char* w = (char*)d_ws;
    auto alloc = [&](size_t bytes) -> void* {
        void* p = (void*)w;
        w += (bytes + 511) & ~(size_t)511;
        return p;
    };
    int*      cursor    = (int*)alloc((size_t)N * 4);
    int*      edge_src  = (int*)alloc((size_t)N * CAP * 4);   // 12.8 MB buckets
    uint4*    wfrag     = (uint4*)alloc((size_t)3 * 2048 * 16);
    unsigned* hwD       = (unsigned*)alloc((size_t)(N + 64) * 128);  // fp8 table + pad row
    unsigned* hbA       = (unsigned*)alloc((size_t)N * 64 * 4);
    unsigned* hbB       = (unsigned*)alloc((size_t)N * 64 * 4);
    float*    partial   = (float*)alloc((size_t)NGRAPH * SUB * NCH * 4);
    int*      gstart    = (int*)alloc((size_t)(NGRAPH + 1) * 4);

    int gE = (E + 255) / 256;
    int gN = (N + 255) / 256;

    k_setup<<<24 + 2 * gN, 256, 0, stream>>>(W1, W2, W3, wfrag, batch, gstart, cursor, N, gN);
    k_fill<<<gE * 8, 256, 0, stream>>>(src, dst, cursor, edge_src, E, N);

    int gM = (N + 63) / 64;
    int gA = (N + 3) / 4;
    // layer 1 (reads fp32 x directly)
    k_mmgemm<<<gM, 256, 0, stream>>>(x, wfrag, cursor, hwD, N, 1);
    k_gather<<<gA, 256, 0, stream>>>((const unsigned short*)hwD, b1, cursor, edge_src, hbA, N);
    // layer 2
    k_mmgemm<<<gM, 256, 0, stream>>>(hbA, wfrag + 2048, cursor, hwD, N, 0);
    k_gather<<<gA, 256, 0, stream>>>((const unsigned short*)hwD, b2, cursor, edge_src, hbB, N);
    // layer 3
    k_mmgemm<<<gM, 256, 0, stream>>>(hbB, wfrag + 4096, cursor, hwD, N, 0);
    k_gather<<<gA, 256, 0, stream>>>((const unsigned short*)hwD, b3, cursor, edge_src, hbA, N);

    k_poolA<<<NGRAPH * SUB, 256, 0, stream>>>(hbA, gstart, partial);
    k_finalize<<<NGRAPH, 128, 0, stream>>>(partial, gstart, Wc, bc, out);
}